// Round 6
// baseline (180.949 us; speedup 1.0000x reference)
//
#include <hip/hip_runtime.h>

#define HW    3136
#define CIN   64
#define MIDC  32
#define HEADS 8
#define DTOT  256
#define COUTC 64
#define WDIM  56
#define QT    16
#define NKT   49
#define L2E   1.4426950408889634f

typedef unsigned short ushort_t;
typedef unsigned int   uint_t;
typedef _Float16 f16;
typedef __attribute__((ext_vector_type(8))) _Float16 half8;
typedef __attribute__((ext_vector_type(2))) __fp16  fp16x2;
typedef __attribute__((ext_vector_type(4))) float f32x4;

union HU { fp16x2 h; uint_t u; };
__device__ __forceinline__ uint_t pkh(float a, float b) {
    HU u; u.h = __builtin_amdgcn_cvt_pkrtz(a, b); return u.u;
}

// ---------------- Kernel 1: QKV 1x1 conv (round-2 structure, f16 out) --------
// grid (7, 256): block y = output channel d; thread handles 2 positions.
// outputs qf/kf/vf: f16 [d][pos]
__global__ __launch_bounds__(256) void qkv_kernel(
    const float* __restrict__ x,
    const float* __restrict__ Wq, const float* __restrict__ bq,
    const float* __restrict__ Wk, const float* __restrict__ bk,
    const float* __restrict__ Wv, const float* __restrict__ bv,
    f16* __restrict__ qf, f16* __restrict__ kf, f16* __restrict__ vf)
{
    int j = blockIdx.x * 256 + threadIdx.x;   // position pair index
    int d = blockIdx.y;
    if (j >= HW / 2) return;
    int p = 2 * j;
    float aq0 = bq[d], aq1 = aq0;
    float ak0 = bk[d], ak1 = ak0;
    float av0 = bv[d], av1 = av0;
    #pragma unroll 8
    for (int c = 0; c < CIN; ++c) {
        float2 xv = *(const float2*)&x[c * HW + p];   // coalesced 8B
        float wq = Wq[d * CIN + c], wk = Wk[d * CIN + c], wv = Wv[d * CIN + c];
        aq0 += wq * xv.x; aq1 += wq * xv.y;
        ak0 += wk * xv.x; ak1 += wk * xv.y;
        av0 += wv * xv.x; av1 += wv * xv.y;
    }
    *(uint_t*)&qf[(size_t)d * HW + p] = pkh(aq0, aq1);
    *(uint_t*)&kf[(size_t)d * HW + p] = pkh(ak0, ak1);
    *(uint_t*)&vf[(size_t)d * HW + p] = pkh(av0, av1);
}

// ---------------- Kernel 2a: repack Q,K -> [h][pos][32] via LDS transpose ----
// grid (49, 8): 64-position tile x head.
__global__ __launch_bounds__(256) void repack_qk_kernel(
    const f16* __restrict__ qf, const f16* __restrict__ kf,
    f16* __restrict__ qh, f16* __restrict__ kh)
{
    __shared__ f16 Tq[64][40];   // pad 40: keeps 16B alignment for row reads
    __shared__ f16 Tk[64][40];
    const int tid = threadIdx.x;
    const int h = blockIdx.y, p0 = blockIdx.x * 64;
    {
        int m = tid >> 3, pi = tid & 7;          // m: mid channel, 8 pos-chunks
        size_t src = (size_t)(m * HEADS + h) * HW + p0 + pi * 8;
        uint4 vq = *(const uint4*)&qf[src];
        uint4 vk = *(const uint4*)&kf[src];
        const f16* eq = (const f16*)&vq;
        const f16* ek = (const f16*)&vk;
        #pragma unroll
        for (int i = 0; i < 8; ++i) {
            Tq[pi * 8 + i][m] = eq[i];
            Tk[pi * 8 + i][m] = ek[i];
        }
    }
    __syncthreads();
    {
        int p = tid >> 2, ck = (tid & 3) * 8;
        size_t dst = (size_t)h * HW * MIDC + (size_t)(p0 + p) * MIDC + ck;
        *(uint4*)&qh[dst] = *(const uint4*)&Tq[p][ck];
        *(uint4*)&kh[dst] = *(const uint4*)&Tk[p][ck];
    }
}

// ---------------- Kernel 2b: repack V -> [h*32+m][pos] (row permute) ---------
__global__ __launch_bounds__(256) void repack_v_kernel(
    const f16* __restrict__ vf, f16* __restrict__ vh)
{
    int j = blockIdx.x * 256 + threadIdx.x;
    int r = blockIdx.y;                 // dst row = h*32+m
    if (j >= HW / 2) return;
    int h = r >> 5, m = r & 31;
    *(uint_t*)&vh[(size_t)r * HW + 2 * j] =
        *(const uint_t*)&vf[(size_t)(m * HEADS + h) * HW + 2 * j];
}

// ---------------- Kernel 3: MFMA flash attention (f16, max-free) -------------
// grid (196, 8), 256 threads = 4 waves, K-split by wave.
__global__ __launch_bounds__(256) void attn_kernel(
    const f16* __restrict__ qh, const f16* __restrict__ kh,
    const f16* __restrict__ vh,
    const float* __restrict__ rowt, const float* __restrict__ colt,
    float* __restrict__ ob)
{
    __shared__ f16   Qs[QT][MIDC];                  // 1 KB
    __shared__ float Rb[QT][57];                    // 3648 B (idx 56 = wrap pad)
    __shared__ float Cb[QT][60];                    // 3840 B (56..59 duplicate 0..3)
    __shared__ __align__(16) char pool[9728];       // P[4][16][72] f16 (9216B),
                                                    // aliased by merge bufs
    f16* PlBase = (f16*)pool;

    const int tid   = threadIdx.x;
    const int wave  = tid >> 6, lane = tid & 63;
    const int h     = blockIdx.y;
    const int qbase = blockIdx.x * QT;
    const float c1  = 0.125f * L2E;

    const f16* Qh = qh + (size_t)h * HW * MIDC;
    const f16* Kh = kh + (size_t)h * HW * MIDC;
    const f16* Vh = vh + (size_t)h * MIDC * HW;     // [ch][pos]

    if (tid < 64) {
        int r = tid >> 2, c = (tid & 3) * 8;
        *(uint4*)&Qs[r][c] = *(const uint4*)&Qh[(size_t)(qbase + r) * MIDC + c];
    }
    __syncthreads();

    // bias tables (c1 folded in). Rb[q][56]=0 (read-but-never-selected pad).
    for (int idx = tid; idx < QT * 57; idx += 256) {
        int qL2 = idx / 57, kp = idx % 57;
        int qg = qbase + qL2, qi = qg / WDIM;
        float s = 0.f;
        if (kp < 56) {
            const float* rt = &rowt[(kp - qi + WDIM - 1) * 16];
            #pragma unroll
            for (int c = 0; c < 16; ++c) s += (float)Qs[qL2][c] * rt[c];
            s *= c1;
        }
        Rb[qL2][kp] = s;
    }
    for (int idx = tid; idx < QT * 60; idx += 256) {
        int qL2 = idx / 60, kp = idx % 60;
        int kpp = (kp < 56) ? kp : kp - 56;
        int qg = qbase + qL2, qj = qg % WDIM;
        const float* ct = &colt[(kpp - qj + WDIM - 1) * 16];
        float s = 0.f;
        #pragma unroll
        for (int c = 0; c < 16; ++c) s += (float)Qs[qL2][16 + c] * ct[c];
        Cb[qL2][kp] = s * c1;
    }
    __syncthreads();

    const int qL  = lane & 15;
    const int grp = lane >> 4;
    half8 qfrag = *(const half8*)&Qs[qL][grp * 8];

    float lacc = 0.f;
    f32x4 o0 = {0.f,0.f,0.f,0.f}, o1 = {0.f,0.f,0.f,0.f};

    int ki_s[4], kj_s[4];
    #pragma unroll
    for (int s = 0; s < 4; ++s) {
        int key0 = wave * 64 + s * 16 + grp * 4;
        ki_s[s] = key0 / WDIM;
        kj_s[s] = key0 % WDIM;
    }

    f16* Pw = PlBase + wave * (QT * 72);

    for (int kt = wave; kt < NKT; kt += 4) {
        const int kb0 = kt * 64;
        half8 kfr[4];
        #pragma unroll
        for (int s = 0; s < 4; ++s)
            kfr[s] = *(const half8*)&Kh[(size_t)(kb0 + s*16 + qL) * MIDC + grp*8];
        half8 vfr[2][2];
        #pragma unroll
        for (int ch = 0; ch < 2; ++ch)
            #pragma unroll
            for (int khf = 0; khf < 2; ++khf)
                vfr[ch][khf] = *(const half8*)
                    &Vh[(size_t)(ch*16 + qL) * HW + kb0 + khf*32 + grp*8];

        // S^T = K . Q^T
        f32x4 sc[4];
        #pragma unroll
        for (int s = 0; s < 4; ++s) {
            f32x4 z = {0.f,0.f,0.f,0.f};
            sc[s] = __builtin_amdgcn_mfma_f32_16x16x32_f16(kfr[s], qfrag, z, 0,0,0);
        }

        // max-free softmax accumulate (scores are bounded ~|1.5| in log2 domain)
        #pragma unroll
        for (int s = 0; s < 4; ++s) {
            int kj0 = kj_s[s];
            const float* rb = &Rb[qL][ki_s[s]];
            float rb0 = rb[0], rb1 = rb[1];              // ds_read2_b32
            const float* cb = &Cb[qL][kj0];
            float cb0 = cb[0], cb1 = cb[1], cb2 = cb[2], cb3 = cb[3]; // 2x read2
            float r1 = (kj0 >= 55) ? rb1 : rb0;          // row-wrap selects
            float r2 = (kj0 >= 54) ? rb1 : rb0;
            float r3 = (kj0 >= 53) ? rb1 : rb0;
            float e0 = __builtin_amdgcn_exp2f(fmaf(sc[s][0], c1, rb0 + cb0));
            float e1 = __builtin_amdgcn_exp2f(fmaf(sc[s][1], c1, r1 + cb1));
            float e2 = __builtin_amdgcn_exp2f(fmaf(sc[s][2], c1, r2 + cb2));
            float e3 = __builtin_amdgcn_exp2f(fmaf(sc[s][3], c1, r3 + cb3));
            lacc += (e0 + e1) + (e2 + e3);
            uint2 w2; w2.x = pkh(e0, e1); w2.y = pkh(e2, e3);
            *(uint2*)&Pw[qL * 72 + s * 16 + grp * 4] = w2;
        }

        // O^T += V^T . P^T
        #pragma unroll
        for (int khf = 0; khf < 2; ++khf) {
            half8 pf = *(const half8*)&Pw[qL * 72 + khf * 32 + grp * 8];
            o0 = __builtin_amdgcn_mfma_f32_16x16x32_f16(vfr[0][khf], pf, o0, 0,0,0);
            o1 = __builtin_amdgcn_mfma_f32_16x16x32_f16(vfr[1][khf], pf, o1, 0,0,0);
        }

        #pragma unroll
        for (int s = 0; s < 4; ++s) {            // advance keys by 256
            kj_s[s] += 32;
            if (kj_s[s] >= WDIM) { kj_s[s] -= WDIM; ki_s[s] += 5; }
            else                 { ki_s[s] += 4; }
        }
    }

    // per-query l for this wave (sum over the 4 lane-groups)
    lacc += __shfl_xor(lacc, 16);
    lacc += __shfl_xor(lacc, 32);

    // ---- merge 4 waves: plain sums (no max weighting needed) ----
    __syncthreads();
    float* MOb = (float*)pool;                   // [4][16][36]
    float* Ll  = MOb + 4 * 16 * 36;              // [4][16]
    *(f32x4*)&MOb[(wave*16 + qL)*36 + grp*4]      = o0;
    *(f32x4*)&MOb[(wave*16 + qL)*36 + 16 + grp*4] = o1;
    if (grp == 0) Ll[wave*16 + qL] = lacc;
    __syncthreads();

    {
        int q = tid & 15, cp = tid >> 4;         // cp: channel pair 0..15
        float l = (Ll[q] + Ll[16+q]) + (Ll[32+q] + Ll[48+q]);
        float a0 = 0.f, a1 = 0.f;
        int ch0 = cp * 2;
        #pragma unroll
        for (int w = 0; w < 4; ++w) {
            a0 += MOb[(w*16+q)*36 + ch0];
            a1 += MOb[(w*16+q)*36 + ch0 + 1];
        }
        float invl = 1.f / l;
        int qg = qbase + q;
        ob[(size_t)(ch0       * HEADS + h) * HW + qg] = a0 * invl;   // d = m*8+h
        ob[(size_t)((ch0 + 1) * HEADS + h) * HW + qg] = a1 * invl;
    }
}

// ---------------- Kernel 4: output 1x1 conv (fp32 ws -> fp32 out) ------------
__global__ __launch_bounds__(256) void outproj_kernel(
    const float* __restrict__ ob, const float* __restrict__ Wo,
    const float* __restrict__ bo, float* __restrict__ out)
{
    int p = blockIdx.x * 256 + threadIdx.x;
    int d = blockIdx.y;
    if (p >= HW) return;
    float s = bo[d];
    #pragma unroll 8
    for (int c = 0; c < DTOT; ++c)
        s += Wo[d * DTOT + c] * ob[(size_t)c * HW + p];   // sequential rows
    out[d * HW + p] = s;
}

extern "C" void kernel_launch(void* const* d_in, const int* in_sizes, int n_in,
                              void* d_out, int out_size, void* d_ws, size_t ws_size,
                              hipStream_t stream)
{
    const float* x    = (const float*)d_in[0];
    const float* Wq   = (const float*)d_in[1];
    const float* bq   = (const float*)d_in[2];
    const float* Wk   = (const float*)d_in[3];
    const float* bk   = (const float*)d_in[4];
    const float* Wv   = (const float*)d_in[5];
    const float* bv   = (const float*)d_in[6];
    const float* Wo   = (const float*)d_in[7];
    const float* bo   = (const float*)d_in[8];
    const float* rowt = (const float*)d_in[9];
    const float* colt = (const float*)d_in[10];
    float* out = (float*)d_out;

    const size_t N = (size_t)DTOT * HW;          // 802816
    f16* qf = (f16*)d_ws;                        // [d][pos] f16
    f16* kf = qf + N;
    f16* vf = kf + N;
    f16* qh = vf + N;                            // [h][pos][32]
    f16* kh = qh + N;
    f16* vh = kh + N;                            // [h*32+m][pos]
    float* ob = (float*)(vh + N);                // [d][pos] fp32, 3.2 MB

    qkv_kernel<<<dim3(7, DTOT), 256, 0, stream>>>(x, Wq, bq, Wk, bk, Wv, bv,
                                                   qf, kf, vf);
    repack_qk_kernel<<<dim3(HW / 64, HEADS), 256, 0, stream>>>(qf, kf, qh, kh);
    repack_v_kernel<<<dim3(7, DTOT), 256, 0, stream>>>(vf, vh);
    attn_kernel<<<dim3(HW / QT, HEADS), 256, 0, stream>>>(qh, kh, vh, rowt, colt, ob);
    outproj_kernel<<<dim3(13, COUTC), 256, 0, stream>>>(ob, Wo, bo, out);
}

// Round 7
// 173.924 us; speedup vs baseline: 1.0404x; 1.0404x over previous
//
#include <hip/hip_runtime.h>

#define HW    3136
#define CIN   64
#define MIDC  32
#define HEADS 8
#define DTOT  256
#define COUTC 64
#define WDIM  56
#define QT    16
#define NKT   49
#define L2E   1.4426950408889634f

typedef unsigned short ushort_t;
typedef unsigned int   uint_t;
typedef _Float16 f16;
typedef __attribute__((ext_vector_type(8))) _Float16 half8;
typedef __attribute__((ext_vector_type(2))) __fp16  fp16x2;
typedef __attribute__((ext_vector_type(4))) float f32x4;

union HU { fp16x2 h; uint_t u; };
__device__ __forceinline__ uint_t pkh(float a, float b) {
    HU u; u.h = __builtin_amdgcn_cvt_pkrtz(a, b); return u.u;
}

// ---------------- Kernel 1: fused QKV conv + layout (fp32 in -> f16 ws) ------
// Direct outputs: qh,kh [h][pos][32]; vh [h*32+m][pos].
// grid (98, 8): 32-position tile x head. x-tile + transposed weights in LDS.
__global__ __launch_bounds__(256) void qkv_fused_kernel(
    const float* __restrict__ x,
    const float* __restrict__ Wq, const float* __restrict__ bq,
    const float* __restrict__ Wk, const float* __restrict__ bk,
    const float* __restrict__ Wv, const float* __restrict__ bv,
    f16* __restrict__ qh, f16* __restrict__ kh, f16* __restrict__ vh)
{
    __shared__ float xs[64][36];        // [ch][pos] pad 36 (b128-write aligned)
    __shared__ float Wlq[64][34];       // [c][m] transposed, pad 34 (b64 aligned)
    __shared__ float Wlk[64][34];
    __shared__ float Wlv[64][34];

    const int tid = threadIdx.x;
    const int h   = blockIdx.y;
    const int P0  = blockIdx.x * 32;

    {   // stage x tile: 64 ch x 32 pos, 8 floats/thread
        int c = tid >> 2, g = tid & 3;
        const float* src = &x[(size_t)c * HW + P0 + g * 8];
        float4 v0 = *(const float4*)src;
        float4 v1 = *(const float4*)(src + 4);
        *(float4*)&xs[c][g * 8]     = v0;
        *(float4*)&xs[c][g * 8 + 4] = v1;
    }
    {   // stage weights transposed: thread: m = tid>>3, c8 = (tid&7)*8
        int m = tid >> 3, c8 = (tid & 7) * 8;
        size_t row = (size_t)(m * HEADS + h) * CIN + c8;
        float4 a0 = *(const float4*)&Wq[row], a1 = *(const float4*)&Wq[row + 4];
        float4 b0 = *(const float4*)&Wk[row], b1 = *(const float4*)&Wk[row + 4];
        float4 c0 = *(const float4*)&Wv[row], c1 = *(const float4*)&Wv[row + 4];
        #pragma unroll
        for (int i = 0; i < 4; ++i) {
            Wlq[c8 + i][m]     = ((const float*)&a0)[i];
            Wlq[c8 + 4 + i][m] = ((const float*)&a1)[i];
            Wlk[c8 + i][m]     = ((const float*)&b0)[i];
            Wlk[c8 + 4 + i][m] = ((const float*)&b1)[i];
            Wlv[c8 + i][m]     = ((const float*)&c0)[i];
            Wlv[c8 + 4 + i][m] = ((const float*)&c1)[i];
        }
    }
    __syncthreads();

    // compute: thread owns channels (m0, m0+1) x positions (p0, p0+1)
    const int a  = tid & 15, pg = tid >> 4;
    const int m0 = a * 2,    p0 = pg * 2;
    const int d0 = m0 * HEADS + h, d1 = d0 + HEADS;

    float q00 = bq[d0], q01 = q00, q10 = bq[d1], q11 = q10;
    float k00 = bk[d0], k01 = k00, k10 = bk[d1], k11 = k10;
    float v00 = bv[d0], v01 = v00, v10 = bv[d1], v11 = v10;

    #pragma unroll 8
    for (int c = 0; c < CIN; ++c) {
        float x0 = xs[c][p0], x1 = xs[c][p0 + 1];          // b64 broadcast
        float wq0 = Wlq[c][m0], wq1 = Wlq[c][m0 + 1];      // b64, conflict-free
        float wk0 = Wlk[c][m0], wk1 = Wlk[c][m0 + 1];
        float wv0 = Wlv[c][m0], wv1 = Wlv[c][m0 + 1];
        q00 += wq0 * x0; q01 += wq0 * x1; q10 += wq1 * x0; q11 += wq1 * x1;
        k00 += wk0 * x0; k01 += wk0 * x1; k10 += wk1 * x0; k11 += wk1 * x1;
        v00 += wv0 * x0; v01 += wv0 * x1; v10 += wv1 * x0; v11 += wv1 * x1;
    }

    // stores: q/k at [h][P0+p][m0..m0+1] (4B), v at rows h*32+m (4B, 2 pos)
    size_t qk0 = (size_t)h * HW * MIDC + (size_t)(P0 + p0) * MIDC + m0;
    *(uint_t*)&qh[qk0]        = pkh(q00, q10);
    *(uint_t*)&qh[qk0 + MIDC] = pkh(q01, q11);
    *(uint_t*)&kh[qk0]        = pkh(k00, k10);
    *(uint_t*)&kh[qk0 + MIDC] = pkh(k01, k11);
    size_t vb0 = (size_t)(h * MIDC + m0) * HW + P0 + p0;
    *(uint_t*)&vh[vb0]      = pkh(v00, v01);
    *(uint_t*)&vh[vb0 + HW] = pkh(v10, v11);
}

// ---------------- Kernel 2: MFMA flash attention (f16, max-free, prefetch) ---
// grid (196, 8), 256 threads = 4 waves, K-split by wave.
__global__ __launch_bounds__(256, 4) void attn_kernel(
    const f16* __restrict__ qh, const f16* __restrict__ kh,
    const f16* __restrict__ vh,
    const float* __restrict__ rowt, const float* __restrict__ colt,
    float* __restrict__ ob)
{
    __shared__ f16   Qs[QT][MIDC];                  // 1 KB
    __shared__ float Rb[QT][57];                    // idx 56 = wrap pad (never selected)
    __shared__ float Cb[QT][60];                    // 56..59 duplicate 0..3
    __shared__ __align__(16) char pool[9728];       // P[4][16][72] f16, aliased by merge
    f16* PlBase = (f16*)pool;

    const int tid   = threadIdx.x;
    const int wave  = tid >> 6, lane = tid & 63;
    const int h     = blockIdx.y;
    const int qbase = blockIdx.x * QT;
    const float c1  = 0.125f * L2E;

    const f16* Qh = qh + (size_t)h * HW * MIDC;
    const f16* Kh = kh + (size_t)h * HW * MIDC;
    const f16* Vh = vh + (size_t)h * MIDC * HW;     // [ch][pos]

    if (tid < 64) {
        int r = tid >> 2, c = (tid & 3) * 8;
        *(uint4*)&Qs[r][c] = *(const uint4*)&Qh[(size_t)(qbase + r) * MIDC + c];
    }
    __syncthreads();

    for (int idx = tid; idx < QT * 57; idx += 256) {
        int qL2 = idx / 57, kp = idx % 57;
        int qg = qbase + qL2, qi = qg / WDIM;
        float s = 0.f;
        if (kp < 56) {
            const float* rt = &rowt[(kp - qi + WDIM - 1) * 16];
            #pragma unroll
            for (int c = 0; c < 16; ++c) s += (float)Qs[qL2][c] * rt[c];
            s *= c1;
        }
        Rb[qL2][kp] = s;
    }
    for (int idx = tid; idx < QT * 60; idx += 256) {
        int qL2 = idx / 60, kp = idx % 60;
        int kpp = (kp < 56) ? kp : kp - 56;
        int qg = qbase + qL2, qj = qg % WDIM;
        const float* ct = &colt[(kpp - qj + WDIM - 1) * 16];
        float s = 0.f;
        #pragma unroll
        for (int c = 0; c < 16; ++c) s += (float)Qs[qL2][16 + c] * ct[c];
        Cb[qL2][kp] = s * c1;
    }
    __syncthreads();

    const int qL  = lane & 15;
    const int grp = lane >> 4;
    half8 qfrag = *(const half8*)&Qs[qL][grp * 8];

    float lacc = 0.f;
    f32x4 o0 = {0.f,0.f,0.f,0.f}, o1 = {0.f,0.f,0.f,0.f};

    int ki_s[4], kj_s[4];
    #pragma unroll
    for (int s = 0; s < 4; ++s) {
        int key0 = wave * 64 + s * 16 + grp * 4;
        ki_s[s] = key0 / WDIM;
        kj_s[s] = key0 % WDIM;
    }

    f16* Pw = PlBase + wave * (QT * 72);

    // preload first tile's fragments
    half8 kfr[4], vfr[2][2];
    {
        const int kb0 = wave * 64;
        #pragma unroll
        for (int s = 0; s < 4; ++s)
            kfr[s] = *(const half8*)&Kh[(size_t)(kb0 + s*16 + qL) * MIDC + grp*8];
        #pragma unroll
        for (int ch = 0; ch < 2; ++ch)
            #pragma unroll
            for (int khf = 0; khf < 2; ++khf)
                vfr[ch][khf] = *(const half8*)
                    &Vh[(size_t)(ch*16 + qL) * HW + kb0 + khf*32 + grp*8];
    }

    for (int kt = wave; kt < NKT; kt += 4) {
        // S^T = K . Q^T (consumes current kfr)
        f32x4 sc[4];
        #pragma unroll
        for (int s = 0; s < 4; ++s) {
            f32x4 z = {0.f,0.f,0.f,0.f};
            sc[s] = __builtin_amdgcn_mfma_f32_16x16x32_f16(kfr[s], qfrag, z, 0,0,0);
        }

        // prefetch next tile's K/V (flies during softmax + PV)
        const int ktn = kt + 4;
        half8 kfn[4], vfn[2][2];
        if (ktn < NKT) {
            const int kbn = ktn * 64;
            #pragma unroll
            for (int s = 0; s < 4; ++s)
                kfn[s] = *(const half8*)&Kh[(size_t)(kbn + s*16 + qL) * MIDC + grp*8];
            #pragma unroll
            for (int ch = 0; ch < 2; ++ch)
                #pragma unroll
                for (int khf = 0; khf < 2; ++khf)
                    vfn[ch][khf] = *(const half8*)
                        &Vh[(size_t)(ch*16 + qL) * HW + kbn + khf*32 + grp*8];
        }

        // max-free softmax (log2 domain, scores bounded ~|1.5|)
        #pragma unroll
        for (int s = 0; s < 4; ++s) {
            int kj0 = kj_s[s];
            const float* rb = &Rb[qL][ki_s[s]];
            float rb0 = rb[0], rb1 = rb[1];
            const float* cb = &Cb[qL][kj0];
            float cb0 = cb[0], cb1 = cb[1], cb2 = cb[2], cb3 = cb[3];
            float r1 = (kj0 >= 55) ? rb1 : rb0;
            float r2 = (kj0 >= 54) ? rb1 : rb0;
            float r3 = (kj0 >= 53) ? rb1 : rb0;
            float e0 = __builtin_amdgcn_exp2f(fmaf(sc[s][0], c1, rb0 + cb0));
            float e1 = __builtin_amdgcn_exp2f(fmaf(sc[s][1], c1, r1 + cb1));
            float e2 = __builtin_amdgcn_exp2f(fmaf(sc[s][2], c1, r2 + cb2));
            float e3 = __builtin_amdgcn_exp2f(fmaf(sc[s][3], c1, r3 + cb3));
            lacc += (e0 + e1) + (e2 + e3);
            uint2 w2; w2.x = pkh(e0, e1); w2.y = pkh(e2, e3);
            *(uint2*)&Pw[qL * 72 + s * 16 + grp * 4] = w2;
        }

        // O^T += V^T . P^T (consumes current vfr)
        #pragma unroll
        for (int khf = 0; khf < 2; ++khf) {
            half8 pf = *(const half8*)&Pw[qL * 72 + khf * 32 + grp * 8];
            o0 = __builtin_amdgcn_mfma_f32_16x16x32_f16(vfr[0][khf], pf, o0, 0,0,0);
            o1 = __builtin_amdgcn_mfma_f32_16x16x32_f16(vfr[1][khf], pf, o1, 0,0,0);
        }

        // rotate prefetched fragments in, advance key coords by 256
        if (ktn < NKT) {
            #pragma unroll
            for (int s = 0; s < 4; ++s) kfr[s] = kfn[s];
            #pragma unroll
            for (int ch = 0; ch < 2; ++ch) {
                vfr[ch][0] = vfn[ch][0]; vfr[ch][1] = vfn[ch][1];
            }
        }
        #pragma unroll
        for (int s = 0; s < 4; ++s) {
            kj_s[s] += 32;
            if (kj_s[s] >= WDIM) { kj_s[s] -= WDIM; ki_s[s] += 5; }
            else                 { ki_s[s] += 4; }
        }
    }

    lacc += __shfl_xor(lacc, 16);
    lacc += __shfl_xor(lacc, 32);

    // merge 4 waves: plain sums (max-free)
    __syncthreads();
    float* MOb = (float*)pool;                   // [4][16][36]
    float* Ll  = MOb + 4 * 16 * 36;              // [4][16]
    *(f32x4*)&MOb[(wave*16 + qL)*36 + grp*4]      = o0;
    *(f32x4*)&MOb[(wave*16 + qL)*36 + 16 + grp*4] = o1;
    if (grp == 0) Ll[wave*16 + qL] = lacc;
    __syncthreads();

    {
        int q = tid & 15, cp = tid >> 4;
        float l = (Ll[q] + Ll[16+q]) + (Ll[32+q] + Ll[48+q]);
        float a0 = 0.f, a1 = 0.f;
        int ch0 = cp * 2;
        #pragma unroll
        for (int w = 0; w < 4; ++w) {
            a0 += MOb[(w*16+q)*36 + ch0];
            a1 += MOb[(w*16+q)*36 + ch0 + 1];
        }
        float invl = 1.f / l;
        int qg = qbase + q;
        ob[(size_t)(ch0       * HEADS + h) * HW + qg] = a0 * invl;   // d = m*8+h
        ob[(size_t)((ch0 + 1) * HEADS + h) * HW + qg] = a1 * invl;
    }
}

// ---------------- Kernel 3: output 1x1 conv (fp32 ws -> fp32 out) ------------
__global__ __launch_bounds__(256) void outproj_kernel(
    const float* __restrict__ ob, const float* __restrict__ Wo,
    const float* __restrict__ bo, float* __restrict__ out)
{
    int p = blockIdx.x * 256 + threadIdx.x;
    int d = blockIdx.y;
    if (p >= HW) return;
    float s = bo[d];
    #pragma unroll 8
    for (int c = 0; c < DTOT; ++c)
        s += Wo[d * DTOT + c] * ob[(size_t)c * HW + p];
    out[d * HW + p] = s;
}

extern "C" void kernel_launch(void* const* d_in, const int* in_sizes, int n_in,
                              void* d_out, int out_size, void* d_ws, size_t ws_size,
                              hipStream_t stream)
{
    const float* x    = (const float*)d_in[0];
    const float* Wq   = (const float*)d_in[1];
    const float* bq   = (const float*)d_in[2];
    const float* Wk   = (const float*)d_in[3];
    const float* bk   = (const float*)d_in[4];
    const float* Wv   = (const float*)d_in[5];
    const float* bv   = (const float*)d_in[6];
    const float* Wo   = (const float*)d_in[7];
    const float* bo   = (const float*)d_in[8];
    const float* rowt = (const float*)d_in[9];
    const float* colt = (const float*)d_in[10];
    float* out = (float*)d_out;

    const size_t N = (size_t)DTOT * HW;          // 802816
    f16* qh = (f16*)d_ws;                        // [h][pos][32]
    f16* kh = qh + N;
    f16* vh = kh + N;                            // [h*32+m][pos]
    float* ob = (float*)(vh + N);                // [d][pos] fp32, 3.2 MB

    qkv_fused_kernel<<<dim3(HW / 32, HEADS), 256, 0, stream>>>(
        x, Wq, bq, Wk, bk, Wv, bv, qh, kh, vh);
    attn_kernel<<<dim3(HW / QT, HEADS), 256, 0, stream>>>(qh, kh, vh, rowt, colt, ob);
    outproj_kernel<<<dim3(13, COUTC), 256, 0, stream>>>(ob, Wo, bo, out);
}

// Round 8
// 169.350 us; speedup vs baseline: 1.0685x; 1.0270x over previous
//
#include <hip/hip_runtime.h>

#define HW    3136
#define CIN   64
#define MIDC  32
#define HEADS 8
#define DTOT  256
#define COUTC 64
#define WDIM  56
#define QT    16
#define L2E   1.4426950408889634f

typedef unsigned int uint_t;
typedef _Float16 f16;
typedef __attribute__((ext_vector_type(8))) _Float16 half8;
typedef __attribute__((ext_vector_type(2))) __fp16  fp16x2;
typedef __attribute__((ext_vector_type(4))) float f32x4;

union HU { fp16x2 h; uint_t u; };
__device__ __forceinline__ uint_t pkh(float a, float b) {
    HU u; u.h = __builtin_amdgcn_cvt_pkrtz(a, b); return u.u;
}

// ---------------- Kernel 1: fused QKV conv + layout (fp32 in -> f16 ws) ------
__global__ __launch_bounds__(256) void qkv_fused_kernel(
    const float* __restrict__ x,
    const float* __restrict__ Wq, const float* __restrict__ bq,
    const float* __restrict__ Wk, const float* __restrict__ bk,
    const float* __restrict__ Wv, const float* __restrict__ bv,
    f16* __restrict__ qh, f16* __restrict__ kh, f16* __restrict__ vh)
{
    __shared__ float xs[64][36];
    __shared__ float Wlq[64][34];
    __shared__ float Wlk[64][34];
    __shared__ float Wlv[64][34];

    const int tid = threadIdx.x;
    const int h   = blockIdx.y;
    const int P0  = blockIdx.x * 32;

    {   int c = tid >> 2, g = tid & 3;
        const float* src = &x[(size_t)c * HW + P0 + g * 8];
        float4 v0 = *(const float4*)src;
        float4 v1 = *(const float4*)(src + 4);
        *(float4*)&xs[c][g * 8]     = v0;
        *(float4*)&xs[c][g * 8 + 4] = v1;
    }
    {   int m = tid >> 3, c8 = (tid & 7) * 8;
        size_t row = (size_t)(m * HEADS + h) * CIN + c8;
        float4 a0 = *(const float4*)&Wq[row], a1 = *(const float4*)&Wq[row + 4];
        float4 b0 = *(const float4*)&Wk[row], b1 = *(const float4*)&Wk[row + 4];
        float4 c0 = *(const float4*)&Wv[row], c1 = *(const float4*)&Wv[row + 4];
        #pragma unroll
        for (int i = 0; i < 4; ++i) {
            Wlq[c8 + i][m]     = ((const float*)&a0)[i];
            Wlq[c8 + 4 + i][m] = ((const float*)&a1)[i];
            Wlk[c8 + i][m]     = ((const float*)&b0)[i];
            Wlk[c8 + 4 + i][m] = ((const float*)&b1)[i];
            Wlv[c8 + i][m]     = ((const float*)&c0)[i];
            Wlv[c8 + 4 + i][m] = ((const float*)&c1)[i];
        }
    }
    __syncthreads();

    const int a  = tid & 15, pg = tid >> 4;
    const int m0 = a * 2,    p0 = pg * 2;
    const int d0 = m0 * HEADS + h, d1 = d0 + HEADS;

    float q00 = bq[d0], q01 = q00, q10 = bq[d1], q11 = q10;
    float k00 = bk[d0], k01 = k00, k10 = bk[d1], k11 = k10;
    float v00 = bv[d0], v01 = v00, v10 = bv[d1], v11 = v10;

    #pragma unroll 8
    for (int c = 0; c < CIN; ++c) {
        float x0 = xs[c][p0], x1 = xs[c][p0 + 1];
        float wq0 = Wlq[c][m0], wq1 = Wlq[c][m0 + 1];
        float wk0 = Wlk[c][m0], wk1 = Wlk[c][m0 + 1];
        float wv0 = Wlv[c][m0], wv1 = Wlv[c][m0 + 1];
        q00 += wq0 * x0; q01 += wq0 * x1; q10 += wq1 * x0; q11 += wq1 * x1;
        k00 += wk0 * x0; k01 += wk0 * x1; k10 += wk1 * x0; k11 += wk1 * x1;
        v00 += wv0 * x0; v01 += wv0 * x1; v10 += wv1 * x0; v11 += wv1 * x1;
    }

    size_t qk0 = (size_t)h * HW * MIDC + (size_t)(P0 + p0) * MIDC + m0;
    *(uint_t*)&qh[qk0]        = pkh(q00, q10);
    *(uint_t*)&qh[qk0 + MIDC] = pkh(q01, q11);
    *(uint_t*)&kh[qk0]        = pkh(k00, k10);
    *(uint_t*)&kh[qk0 + MIDC] = pkh(k01, k11);
    size_t vb0 = (size_t)(h * MIDC + m0) * HW + P0 + p0;
    *(uint_t*)&vh[vb0]      = pkh(v00, v01);
    *(uint_t*)&vh[vb0 + HW] = pkh(v10, v11);
}

// ---------------- Kernel 2: MFMA flash attention (f16, max-free, 128k/iter) --
// grid (196, 8), 4 waves. Wave w owns key-tile pairs {8j+2w, 8j+2w+1}, j=0..5;
// wave 0 additionally does tile 48. All keys ≡ 0 mod 4 per subtile → no row wrap.
__global__ __launch_bounds__(256, 3) void attn_kernel(
    const f16* __restrict__ qh, const f16* __restrict__ kh,
    const f16* __restrict__ vh,
    const float* __restrict__ rowt, const float* __restrict__ colt,
    float* __restrict__ ob)
{
    __shared__ f16   Qs[QT][MIDC];                  // 1 KB
    __shared__ float Rb[QT][57];                    // row-bias, stride 57
    __shared__ float Cb[QT][60];                    // col-bias, stride 60 (16B align)
    __shared__ __align__(16) char pool[17472];      // P[4][16][136] f16; merge alias
    f16* PlBase = (f16*)pool;

    const int tid   = threadIdx.x;
    const int wave  = tid >> 6, lane = tid & 63;
    const int h     = blockIdx.y;
    const int qbase = blockIdx.x * QT;
    const float c1  = 0.125f * L2E;

    const f16* Qh = qh + (size_t)h * HW * MIDC;
    const f16* Kh = kh + (size_t)h * HW * MIDC;
    const f16* Vh = vh + (size_t)h * MIDC * HW;

    if (tid < 64) {
        int r = tid >> 2, c = (tid & 3) * 8;
        *(uint4*)&Qs[r][c] = *(const uint4*)&Qh[(size_t)(qbase + r) * MIDC + c];
    }
    __syncthreads();

    for (int idx = tid; idx < QT * 56; idx += 256) {
        int qL2 = idx >> 5 >> 1 ? 0 : 0;             // (placeholder avoided)
        qL2 = idx / 56; int kp = idx % 56;
        int qg = qbase + qL2, qi = qg / WDIM, qj = qg % WDIM;
        const float* rt = &rowt[(kp - qi + WDIM - 1) * 16];
        const float* ct = &colt[(kp - qj + WDIM - 1) * 16];
        float s = 0.f, s2 = 0.f;
        #pragma unroll
        for (int c = 0; c < 16; ++c) {
            s  += (float)Qs[qL2][c]      * rt[c];
            s2 += (float)Qs[qL2][16 + c] * ct[c];
        }
        Rb[qL2][kp] = s * c1;
        Cb[qL2][kp] = s2 * c1;
    }
    __syncthreads();

    const int qL  = lane & 15;
    const int grp = lane >> 4;
    half8 qfrag = *(const half8*)&Qs[qL][grp * 8];

    float lacc = 0.f;
    f32x4 o0 = {0.f,0.f,0.f,0.f}, o1 = {0.f,0.f,0.f,0.f};

    // per-subtile key coords, subtiles s=0..7 within the 128-key iteration
    int ki_s[8], kj_s[8];
    #pragma unroll
    for (int s = 0; s < 8; ++s) {
        int key0 = wave * 128 + s * 16 + grp * 4;
        ki_s[s] = key0 / WDIM;                       // magic-mul once
        kj_s[s] = key0 % WDIM;                       // multiple of 4, <= 52
    }

    f16* Pw = PlBase + wave * (QT * 136);

    for (int j = 0; j < 6; ++j) {
        const int base = 512 * j + 128 * wave;

        half8 kfr[8];
        #pragma unroll
        for (int s = 0; s < 8; ++s)
            kfr[s] = *(const half8*)&Kh[(size_t)(base + s*16 + qL) * MIDC + grp*8];
        half8 vfr[2][4];
        #pragma unroll
        for (int ch = 0; ch < 2; ++ch)
            #pragma unroll
            for (int kf2 = 0; kf2 < 4; ++kf2)
                vfr[ch][kf2] = *(const half8*)
                    &Vh[(size_t)(ch*16 + qL) * HW + base + kf2*32 + grp*8];

        f32x4 sc[8];
        #pragma unroll
        for (int s = 0; s < 4; ++s) {
            f32x4 z = {0.f,0.f,0.f,0.f};
            sc[s] = __builtin_amdgcn_mfma_f32_16x16x32_f16(kfr[s], qfrag, z, 0,0,0);
        }
        #pragma unroll
        for (int s = 4; s < 8; ++s) {
            f32x4 z = {0.f,0.f,0.f,0.f};
            sc[s] = __builtin_amdgcn_mfma_f32_16x16x32_f16(kfr[s], qfrag, z, 0,0,0);
        }

        // softmax: no wrap possible (kj <= 52), bias = Rb scalar + Cb b128
        #pragma unroll
        for (int s = 0; s < 8; ++s) {
            float rb = Rb[qL][ki_s[s]];
            const float* cb = &Cb[qL][kj_s[s]];      // 16B-aligned (kj mult of 4)
            float4 cbv = *(const float4*)cb;
            float e0 = __builtin_amdgcn_exp2f(fmaf(sc[s][0], c1, rb + cbv.x));
            float e1 = __builtin_amdgcn_exp2f(fmaf(sc[s][1], c1, rb + cbv.y));
            float e2 = __builtin_amdgcn_exp2f(fmaf(sc[s][2], c1, rb + cbv.z));
            float e3 = __builtin_amdgcn_exp2f(fmaf(sc[s][3], c1, rb + cbv.w));
            lacc += (e0 + e1) + (e2 + e3);
            uint2 w2; w2.x = pkh(e0, e1); w2.y = pkh(e2, e3);
            *(uint2*)&Pw[qL * 136 + s * 16 + grp * 4] = w2;
        }

        // O^T += V^T . P^T over 128 keys (4 k-chunks x 2 ch-halves)
        #pragma unroll
        for (int kf2 = 0; kf2 < 4; ++kf2) {
            half8 pf = *(const half8*)&Pw[qL * 136 + kf2 * 32 + grp * 8];
            o0 = __builtin_amdgcn_mfma_f32_16x16x32_f16(vfr[0][kf2], pf, o0, 0,0,0);
            o1 = __builtin_amdgcn_mfma_f32_16x16x32_f16(vfr[1][kf2], pf, o1, 0,0,0);
        }

        #pragma unroll
        for (int s = 0; s < 8; ++s) {                // advance keys by 512
            kj_s[s] += 8;                             // 512 mod 56
            if (kj_s[s] >= WDIM) { kj_s[s] -= WDIM; ki_s[s] += 10; }
            else                 { ki_s[s] += 9; }
        }
    }

    if (wave == 0) {       // tile 48: keys 3072..3135 (wave-uniform branch)
        const int base = 3072;
        half8 kfr[4];
        #pragma unroll
        for (int s = 0; s < 4; ++s)
            kfr[s] = *(const half8*)&Kh[(size_t)(base + s*16 + qL) * MIDC + grp*8];
        half8 vfr[2][2];
        #pragma unroll
        for (int ch = 0; ch < 2; ++ch)
            #pragma unroll
            for (int kf2 = 0; kf2 < 2; ++kf2)
                vfr[ch][kf2] = *(const half8*)
                    &Vh[(size_t)(ch*16 + qL) * HW + base + kf2*32 + grp*8];
        f32x4 sc[4];
        #pragma unroll
        for (int s = 0; s < 4; ++s) {
            f32x4 z = {0.f,0.f,0.f,0.f};
            sc[s] = __builtin_amdgcn_mfma_f32_16x16x32_f16(kfr[s], qfrag, z, 0,0,0);
        }
        #pragma unroll
        for (int s = 0; s < 4; ++s) {
            int key0 = base + s * 16 + grp * 4;
            int ki = key0 / WDIM, kj = key0 % WDIM;
            float rb = Rb[qL][ki];
            float4 cbv = *(const float4*)&Cb[qL][kj];
            float e0 = __builtin_amdgcn_exp2f(fmaf(sc[s][0], c1, rb + cbv.x));
            float e1 = __builtin_amdgcn_exp2f(fmaf(sc[s][1], c1, rb + cbv.y));
            float e2 = __builtin_amdgcn_exp2f(fmaf(sc[s][2], c1, rb + cbv.z));
            float e3 = __builtin_amdgcn_exp2f(fmaf(sc[s][3], c1, rb + cbv.w));
            lacc += (e0 + e1) + (e2 + e3);
            uint2 w2; w2.x = pkh(e0, e1); w2.y = pkh(e2, e3);
            *(uint2*)&Pw[qL * 136 + s * 16 + grp * 4] = w2;
        }
        #pragma unroll
        for (int kf2 = 0; kf2 < 2; ++kf2) {
            half8 pf = *(const half8*)&Pw[qL * 136 + kf2 * 32 + grp * 8];
            o0 = __builtin_amdgcn_mfma_f32_16x16x32_f16(vfr[0][kf2], pf, o0, 0,0,0);
            o1 = __builtin_amdgcn_mfma_f32_16x16x32_f16(vfr[1][kf2], pf, o1, 0,0,0);
        }
    }

    lacc += __shfl_xor(lacc, 16);
    lacc += __shfl_xor(lacc, 32);

    __syncthreads();
    float* MOb = (float*)pool;                   // [4][16][36]
    float* Ll  = MOb + 4 * 16 * 36;              // [4][16]
    *(f32x4*)&MOb[(wave*16 + qL)*36 + grp*4]      = o0;
    *(f32x4*)&MOb[(wave*16 + qL)*36 + 16 + grp*4] = o1;
    if (grp == 0) Ll[wave*16 + qL] = lacc;
    __syncthreads();

    {
        int q = tid & 15, cp = tid >> 4;
        float l = (Ll[q] + Ll[16+q]) + (Ll[32+q] + Ll[48+q]);
        float a0 = 0.f, a1 = 0.f;
        int ch0 = cp * 2;
        #pragma unroll
        for (int w = 0; w < 4; ++w) {
            a0 += MOb[(w*16+q)*36 + ch0];
            a1 += MOb[(w*16+q)*36 + ch0 + 1];
        }
        float invl = 1.f / l;
        int qg = qbase + q;
        ob[(size_t)(ch0       * HEADS + h) * HW + qg] = a0 * invl;
        ob[(size_t)((ch0 + 1) * HEADS + h) * HW + qg] = a1 * invl;
    }
}

// ---------------- Kernel 3: output 1x1 conv (fp32 ws -> fp32 out) ------------
__global__ __launch_bounds__(256) void outproj_kernel(
    const float* __restrict__ ob, const float* __restrict__ Wo,
    const float* __restrict__ bo, float* __restrict__ out)
{
    int p = blockIdx.x * 256 + threadIdx.x;
    int d = blockIdx.y;
    if (p >= HW) return;
    float s = bo[d];
    #pragma unroll 8
    for (int c = 0; c < DTOT; ++c)
        s += Wo[d * DTOT + c] * ob[(size_t)c * HW + p];
    out[d * HW + p] = s;
}

extern "C" void kernel_launch(void* const* d_in, const int* in_sizes, int n_in,
                              void* d_out, int out_size, void* d_ws, size_t ws_size,
                              hipStream_t stream)
{
    const float* x    = (const float*)d_in[0];
    const float* Wq   = (const float*)d_in[1];
    const float* bq   = (const float*)d_in[2];
    const float* Wk   = (const float*)d_in[3];
    const float* bk   = (const float*)d_in[4];
    const float* Wv   = (const float*)d_in[5];
    const float* bv   = (const float*)d_in[6];
    const float* Wo   = (const float*)d_in[7];
    const float* bo   = (const float*)d_in[8];
    const float* rowt = (const float*)d_in[9];
    const float* colt = (const float*)d_in[10];
    float* out = (float*)d_out;

    const size_t N = (size_t)DTOT * HW;
    f16* qh = (f16*)d_ws;
    f16* kh = qh + N;
    f16* vh = kh + N;
    float* ob = (float*)(vh + N);

    qkv_fused_kernel<<<dim3(HW / 32, HEADS), 256, 0, stream>>>(
        x, Wq, bq, Wk, bk, Wv, bv, qh, kh, vh);
    attn_kernel<<<dim3(HW / QT, HEADS), 256, 0, stream>>>(qh, kh, vh, rowt, colt, ob);
    outproj_kernel<<<dim3(13, COUTC), 256, 0, stream>>>(ob, Wo, bo, out);
}

// Round 9
// 146.178 us; speedup vs baseline: 1.2379x; 1.1585x over previous
//
#include <hip/hip_runtime.h>

#define HW    3136
#define CIN   64
#define MIDC  32
#define HEADS 8
#define DTOT  256
#define COUTC 64
#define WDIM  56
#define QT    32
#define L2E   1.4426950408889634f

typedef unsigned int uint_t;
typedef _Float16 f16;
typedef __attribute__((ext_vector_type(8))) _Float16 half8;
typedef __attribute__((ext_vector_type(2))) __fp16  fp16x2;
typedef __attribute__((ext_vector_type(4))) float f32x4;

union HU { fp16x2 h; uint_t u; };
__device__ __forceinline__ uint_t pkh(float a, float b) {
    HU u; u.h = __builtin_amdgcn_cvt_pkrtz(a, b); return u.u;
}

// ---------------- Kernel 1: fused QKV conv + layout (fp32 in -> f16 ws) ------
__global__ __launch_bounds__(256) void qkv_fused_kernel(
    const float* __restrict__ x,
    const float* __restrict__ Wq, const float* __restrict__ bq,
    const float* __restrict__ Wk, const float* __restrict__ bk,
    const float* __restrict__ Wv, const float* __restrict__ bv,
    f16* __restrict__ qh, f16* __restrict__ kh, f16* __restrict__ vh)
{
    __shared__ float xs[64][36];
    __shared__ float Wlq[64][34];
    __shared__ float Wlk[64][34];
    __shared__ float Wlv[64][34];

    const int tid = threadIdx.x;
    const int h   = blockIdx.y;
    const int P0  = blockIdx.x * 32;

    {   int c = tid >> 2, g = tid & 3;
        const float* src = &x[(size_t)c * HW + P0 + g * 8];
        float4 v0 = *(const float4*)src;
        float4 v1 = *(const float4*)(src + 4);
        *(float4*)&xs[c][g * 8]     = v0;
        *(float4*)&xs[c][g * 8 + 4] = v1;
    }
    {   int m = tid >> 3, c8 = (tid & 7) * 8;
        size_t row = (size_t)(m * HEADS + h) * CIN + c8;
        float4 a0 = *(const float4*)&Wq[row], a1 = *(const float4*)&Wq[row + 4];
        float4 b0 = *(const float4*)&Wk[row], b1 = *(const float4*)&Wk[row + 4];
        float4 c0 = *(const float4*)&Wv[row], c1 = *(const float4*)&Wv[row + 4];
        #pragma unroll
        for (int i = 0; i < 4; ++i) {
            Wlq[c8 + i][m]     = ((const float*)&a0)[i];
            Wlq[c8 + 4 + i][m] = ((const float*)&a1)[i];
            Wlk[c8 + i][m]     = ((const float*)&b0)[i];
            Wlk[c8 + 4 + i][m] = ((const float*)&b1)[i];
            Wlv[c8 + i][m]     = ((const float*)&c0)[i];
            Wlv[c8 + 4 + i][m] = ((const float*)&c1)[i];
        }
    }
    __syncthreads();

    const int a  = tid & 15, pg = tid >> 4;
    const int m0 = a * 2,    p0 = pg * 2;
    const int d0 = m0 * HEADS + h, d1 = d0 + HEADS;

    float q00 = bq[d0], q01 = q00, q10 = bq[d1], q11 = q10;
    float k00 = bk[d0], k01 = k00, k10 = bk[d1], k11 = k10;
    float v00 = bv[d0], v01 = v00, v10 = bv[d1], v11 = v10;

    #pragma unroll 8
    for (int c = 0; c < CIN; ++c) {
        float x0 = xs[c][p0], x1 = xs[c][p0 + 1];
        float wq0 = Wlq[c][m0], wq1 = Wlq[c][m0 + 1];
        float wk0 = Wlk[c][m0], wk1 = Wlk[c][m0 + 1];
        float wv0 = Wlv[c][m0], wv1 = Wlv[c][m0 + 1];
        q00 += wq0 * x0; q01 += wq0 * x1; q10 += wq1 * x0; q11 += wq1 * x1;
        k00 += wk0 * x0; k01 += wk0 * x1; k10 += wk1 * x0; k11 += wk1 * x1;
        v00 += wv0 * x0; v01 += wv0 * x1; v10 += wv1 * x0; v11 += wv1 * x1;
    }

    size_t qk0 = (size_t)h * HW * MIDC + (size_t)(P0 + p0) * MIDC + m0;
    *(uint_t*)&qh[qk0]        = pkh(q00, q10);
    *(uint_t*)&qh[qk0 + MIDC] = pkh(q01, q11);
    *(uint_t*)&kh[qk0]        = pkh(k00, k10);
    *(uint_t*)&kh[qk0 + MIDC] = pkh(k01, k11);
    size_t vb0 = (size_t)(h * MIDC + m0) * HW + P0 + p0;
    *(uint_t*)&vh[vb0]      = pkh(v00, v01);
    *(uint_t*)&vh[vb0 + HW] = pkh(v10, v11);
}

// ---------------- Kernel 2: MFMA flash attention, QT=32, K-split -------------
// grid (98, 8), 4 waves. Wave w owns key-tile pairs {8j+2w, 8j+2w+1}; wave 0
// also does tile 48. Each wave serves 32 queries (2 q-fragments).
__global__ __launch_bounds__(256, 3) void attn_kernel(
    const f16* __restrict__ qh, const f16* __restrict__ kh,
    const f16* __restrict__ vh,
    const float* __restrict__ rowt, const float* __restrict__ colt,
    float* __restrict__ ob)
{
    __shared__ f16   Qs[QT][MIDC];                  // 2 KB
    __shared__ float Rb[QT][57];                    // 7.3 KB
    __shared__ float Cb[QT][60];                    // 7.7 KB (16B-aligned rows)
    __shared__ __align__(16) char pool[18944];      // P[4][16][136] f16; merge alias
    f16* PlBase = (f16*)pool;

    const int tid   = threadIdx.x;
    const int wave  = tid >> 6, lane = tid & 63;
    const int h     = blockIdx.y;
    const int qbase = blockIdx.x * QT;
    const float c1  = 0.125f * L2E;

    const f16* Qh = qh + (size_t)h * HW * MIDC;
    const f16* Kh = kh + (size_t)h * HW * MIDC;
    const f16* Vh = vh + (size_t)h * MIDC * HW;

    if (tid < 128) {
        int r = tid >> 2, c = (tid & 3) * 8;
        *(uint4*)&Qs[r][c] = *(const uint4*)&Qh[(size_t)(qbase + r) * MIDC + c];
    }
    __syncthreads();

    // bias tables: thread owns one q, 7 kp entries; Q-row via 4 b128 reads
    {
        int q = tid >> 3, sub = tid & 7;
        int qg = qbase + q, qi = qg / WDIM, qj = qg % WDIM;
        half8 qr0 = *(const half8*)&Qs[q][0];
        half8 qr1 = *(const half8*)&Qs[q][8];
        half8 qr2 = *(const half8*)&Qs[q][16];
        half8 qr3 = *(const half8*)&Qs[q][24];
        for (int kp = sub; kp < WDIM; kp += 8) {
            const float* rt = &rowt[(kp - qi + WDIM - 1) * 16];
            const float* ct = &colt[(kp - qj + WDIM - 1) * 16];
            float s = 0.f, s2 = 0.f;
            #pragma unroll
            for (int c = 0; c < 8; ++c) {
                s  += (float)qr0[c] * rt[c] + (float)qr1[c] * rt[8 + c];
                s2 += (float)qr2[c] * ct[c] + (float)qr3[c] * ct[8 + c];
            }
            Rb[q][kp] = s * c1;
            Cb[q][kp] = s2 * c1;
        }
    }
    __syncthreads();

    const int qL  = lane & 15;
    const int grp = lane >> 4;
    half8 qfrag[2];
    qfrag[0] = *(const half8*)&Qs[qL][grp * 8];
    qfrag[1] = *(const half8*)&Qs[16 + qL][grp * 8];

    float lacc[2] = {0.f, 0.f};
    f32x4 o[2][2];
    #pragma unroll
    for (int i = 0; i < 2; ++i) { o[i][0] = (f32x4){0,0,0,0}; o[i][1] = (f32x4){0,0,0,0}; }

    int ki_s[8], kj_s[8];
    #pragma unroll
    for (int s = 0; s < 8; ++s) {
        int key0 = wave * 128 + s * 16 + grp * 4;
        ki_s[s] = key0 / WDIM;
        kj_s[s] = key0 % WDIM;                       // multiple of 4, <= 52
    }

    f16* Pw = PlBase + wave * (16 * 136);

    for (int j = 0; j < 6; ++j) {
        const int base = 512 * j + 128 * wave;

        half8 kfr[8];
        #pragma unroll
        for (int s = 0; s < 8; ++s)
            kfr[s] = *(const half8*)&Kh[(size_t)(base + s*16 + qL) * MIDC + grp*8];
        half8 vfr[2][4];
        #pragma unroll
        for (int ch = 0; ch < 2; ++ch)
            #pragma unroll
            for (int kf2 = 0; kf2 < 4; ++kf2)
                vfr[ch][kf2] = *(const half8*)
                    &Vh[(size_t)(ch*16 + qL) * HW + base + kf2*32 + grp*8];

        #pragma unroll
        for (int hf = 0; hf < 2; ++hf) {
            const int qrow = hf * 16 + qL;
            f32x4 sc[8];
            #pragma unroll
            for (int s = 0; s < 8; ++s) {
                f32x4 z = {0.f,0.f,0.f,0.f};
                sc[s] = __builtin_amdgcn_mfma_f32_16x16x32_f16(kfr[s], qfrag[hf], z, 0,0,0);
            }
            #pragma unroll
            for (int s = 0; s < 8; ++s) {
                float rb = Rb[qrow][ki_s[s]];
                float4 cbv = *(const float4*)&Cb[qrow][kj_s[s]];
                float e0 = __builtin_amdgcn_exp2f(fmaf(sc[s][0], c1, rb + cbv.x));
                float e1 = __builtin_amdgcn_exp2f(fmaf(sc[s][1], c1, rb + cbv.y));
                float e2 = __builtin_amdgcn_exp2f(fmaf(sc[s][2], c1, rb + cbv.z));
                float e3 = __builtin_amdgcn_exp2f(fmaf(sc[s][3], c1, rb + cbv.w));
                lacc[hf] += (e0 + e1) + (e2 + e3);
                uint2 w2; w2.x = pkh(e0, e1); w2.y = pkh(e2, e3);
                *(uint2*)&Pw[qL * 136 + s * 16 + grp * 4] = w2;
            }
            #pragma unroll
            for (int kf2 = 0; kf2 < 4; ++kf2) {
                half8 pf = *(const half8*)&Pw[qL * 136 + kf2 * 32 + grp * 8];
                o[hf][0] = __builtin_amdgcn_mfma_f32_16x16x32_f16(vfr[0][kf2], pf, o[hf][0], 0,0,0);
                o[hf][1] = __builtin_amdgcn_mfma_f32_16x16x32_f16(vfr[1][kf2], pf, o[hf][1], 0,0,0);
            }
        }

        #pragma unroll
        for (int s = 0; s < 8; ++s) {                // advance keys by 512
            kj_s[s] += 8;
            if (kj_s[s] >= WDIM) { kj_s[s] -= WDIM; ki_s[s] += 10; }
            else                 { ki_s[s] += 9; }
        }
    }

    if (wave == 0) {       // tile 48: keys 3072..3135
        const int base = 3072;
        half8 kfr[4];
        #pragma unroll
        for (int s = 0; s < 4; ++s)
            kfr[s] = *(const half8*)&Kh[(size_t)(base + s*16 + qL) * MIDC + grp*8];
        half8 vfr[2][2];
        #pragma unroll
        for (int ch = 0; ch < 2; ++ch)
            #pragma unroll
            for (int kf2 = 0; kf2 < 2; ++kf2)
                vfr[ch][kf2] = *(const half8*)
                    &Vh[(size_t)(ch*16 + qL) * HW + base + kf2*32 + grp*8];
        #pragma unroll
        for (int hf = 0; hf < 2; ++hf) {
            const int qrow = hf * 16 + qL;
            f32x4 sc[4];
            #pragma unroll
            for (int s = 0; s < 4; ++s) {
                f32x4 z = {0.f,0.f,0.f,0.f};
                sc[s] = __builtin_amdgcn_mfma_f32_16x16x32_f16(kfr[s], qfrag[hf], z, 0,0,0);
            }
            #pragma unroll
            for (int s = 0; s < 4; ++s) {
                int key0 = base + s * 16 + grp * 4;
                int ki = key0 / WDIM, kj = key0 % WDIM;
                float rb = Rb[qrow][ki];
                float4 cbv = *(const float4*)&Cb[qrow][kj];
                float e0 = __builtin_amdgcn_exp2f(fmaf(sc[s][0], c1, rb + cbv.x));
                float e1 = __builtin_amdgcn_exp2f(fmaf(sc[s][1], c1, rb + cbv.y));
                float e2 = __builtin_amdgcn_exp2f(fmaf(sc[s][2], c1, rb + cbv.z));
                float e3 = __builtin_amdgcn_exp2f(fmaf(sc[s][3], c1, rb + cbv.w));
                lacc[hf] += (e0 + e1) + (e2 + e3);
                uint2 w2; w2.x = pkh(e0, e1); w2.y = pkh(e2, e3);
                *(uint2*)&Pw[qL * 136 + s * 16 + grp * 4] = w2;
            }
            #pragma unroll
            for (int kf2 = 0; kf2 < 2; ++kf2) {
                half8 pf = *(const half8*)&Pw[qL * 136 + kf2 * 32 + grp * 8];
                o[hf][0] = __builtin_amdgcn_mfma_f32_16x16x32_f16(vfr[0][kf2], pf, o[hf][0], 0,0,0);
                o[hf][1] = __builtin_amdgcn_mfma_f32_16x16x32_f16(vfr[1][kf2], pf, o[hf][1], 0,0,0);
            }
        }
    }

    #pragma unroll
    for (int hf = 0; hf < 2; ++hf) {
        lacc[hf] += __shfl_xor(lacc[hf], 16);
        lacc[hf] += __shfl_xor(lacc[hf], 32);
    }

    // merge 4 waves: plain sums
    __syncthreads();
    float* MOb = (float*)pool;                   // [4][32][36]
    float* Ll  = MOb + 4 * 32 * 36;              // [4][32]
    #pragma unroll
    for (int hf = 0; hf < 2; ++hf) {
        int row = wave * 32 + hf * 16 + qL;
        *(f32x4*)&MOb[row * 36 + grp * 4]      = o[hf][0];
        *(f32x4*)&MOb[row * 36 + 16 + grp * 4] = o[hf][1];
        if (grp == 0) Ll[row] = lacc[hf];
    }
    __syncthreads();

    {
        int q = tid & 31, cseg = tid >> 5;       // cseg 0..7 -> 4 channels each
        float l = (Ll[q] + Ll[32+q]) + (Ll[64+q] + Ll[96+q]);
        float invl = 1.f / l;
        int qg = qbase + q;
        #pragma unroll
        for (int i = 0; i < 4; ++i) {
            int ch = cseg * 4 + i;
            float acc = 0.f;
            #pragma unroll
            for (int w = 0; w < 4; ++w)
                acc += MOb[(w*32 + q) * 36 + ch];
            ob[(size_t)(ch * HEADS + h) * HW + qg] = acc * invl;
        }
    }
}

// ---------------- Kernel 3: output 1x1 conv via MFMA -------------------------
// grid (196), 64 threads. C-tile: 64 out-ch x 16 pos, K=256.
__global__ __launch_bounds__(64) void outproj_kernel(
    const float* __restrict__ ob, const float* __restrict__ Wo,
    const float* __restrict__ bo, float* __restrict__ out)
{
    const int lane = threadIdx.x;
    const int qL = lane & 15, grp = lane >> 4;
    const int p = blockIdx.x * 16 + qL;

    f32x4 acc[4];
    #pragma unroll
    for (int mt = 0; mt < 4; ++mt) acc[mt] = (f32x4){0,0,0,0};

    #pragma unroll
    for (int ks = 0; ks < 8; ++ks) {
        // B-frag: ob[k][p], k = ks*32 + grp*8 + j (fp32 [c][pos] layout)
        half8 bf;
        #pragma unroll
        for (int jj = 0; jj < 8; ++jj)
            bf[jj] = (f16)ob[(size_t)(ks * 32 + grp * 8 + jj) * HW + p];
        #pragma unroll
        for (int mt = 0; mt < 4; ++mt) {
            const float* wrow = &Wo[(size_t)(mt * 16 + qL) * DTOT + ks * 32 + grp * 8];
            float4 a0 = *(const float4*)wrow;
            float4 a1 = *(const float4*)(wrow + 4);
            half8 af;
            af[0] = (f16)a0.x; af[1] = (f16)a0.y; af[2] = (f16)a0.z; af[3] = (f16)a0.w;
            af[4] = (f16)a1.x; af[5] = (f16)a1.y; af[6] = (f16)a1.z; af[7] = (f16)a1.w;
            acc[mt] = __builtin_amdgcn_mfma_f32_16x16x32_f16(af, bf, acc[mt], 0, 0, 0);
        }
    }

    #pragma unroll
    for (int mt = 0; mt < 4; ++mt)
        #pragma unroll
        for (int r = 0; r < 4; ++r) {
            int d = mt * 16 + grp * 4 + r;
            out[(size_t)d * HW + p] = acc[mt][r] + bo[d];
        }
}

extern "C" void kernel_launch(void* const* d_in, const int* in_sizes, int n_in,
                              void* d_out, int out_size, void* d_ws, size_t ws_size,
                              hipStream_t stream)
{
    const float* x    = (const float*)d_in[0];
    const float* Wq   = (const float*)d_in[1];
    const float* bq   = (const float*)d_in[2];
    const float* Wk   = (const float*)d_in[3];
    const float* bk   = (const float*)d_in[4];
    const float* Wv   = (const float*)d_in[5];
    const float* bv   = (const float*)d_in[6];
    const float* Wo   = (const float*)d_in[7];
    const float* bo   = (const float*)d_in[8];
    const float* rowt = (const float*)d_in[9];
    const float* colt = (const float*)d_in[10];
    float* out = (float*)d_out;

    const size_t N = (size_t)DTOT * HW;
    f16* qh = (f16*)d_ws;                        // [h][pos][32]
    f16* kh = qh + N;
    f16* vh = kh + N;                            // [h*32+m][pos]
    float* ob = (float*)(vh + N);                // [d][pos] fp32

    qkv_fused_kernel<<<dim3(HW / 32, HEADS), 256, 0, stream>>>(
        x, Wq, bq, Wk, bk, Wv, bv, qh, kh, vh);
    attn_kernel<<<dim3(HW / QT, HEADS), 256, 0, stream>>>(qh, kh, vh, rowt, colt, ob);
    outproj_kernel<<<dim3(HW / 16), 64, 0, stream>>>(ob, Wo, bo, out);
}